// Round 1
// baseline (86.036 us; speedup 1.0000x reference)
//
#include <hip/hip_runtime.h>
#include <hip/hip_bf16.h>
#include <math.h>

typedef short short8 __attribute__((ext_vector_type(8)));
typedef float f32x4 __attribute__((ext_vector_type(4)));

#define NROW 4096
#define DIM  128

__device__ __forceinline__ unsigned short f2bf(float f) {
    unsigned u = __builtin_bit_cast(unsigned, f);
    unsigned r = (u + 0x7fffu + ((u >> 16) & 1u)) >> 16;   // RNE
    return (unsigned short)r;
}

// ---- prep: fp32 row norms, bf16 copy, zero accumulators ----
__global__ __launch_bounds__(256) void prep_kernel(const float* __restrict__ X,
        unsigned short* __restrict__ Xb, float* __restrict__ sq,
        float* __restrict__ rn, float* __restrict__ acc)
{
    int t = threadIdx.x;
    int row = blockIdx.x * 8 + (t >> 5);
    int c = t & 31;
    float4 v = *reinterpret_cast<const float4*>(X + row * DIM + c * 4);
    float p = v.x * v.x + v.y * v.y + v.z * v.z + v.w * v.w;
    p += __shfl_xor(p, 16, 32);
    p += __shfl_xor(p, 8, 32);
    p += __shfl_xor(p, 4, 32);
    p += __shfl_xor(p, 2, 32);
    p += __shfl_xor(p, 1, 32);
    ushort4 h;
    h.x = f2bf(v.x); h.y = f2bf(v.y); h.z = f2bf(v.z); h.w = f2bf(v.w);
    *reinterpret_cast<ushort4*>(Xb + row * DIM + c * 4) = h;
    if (c == 0) { sq[row] = p; rn[row] = 0.0f; }
    if (blockIdx.x == 0 && t < 2) acc[t] = 0.0f;
}

// ---- main pass: tile (128 i) x (64 j) of X.X^T via bf16 MFMA ----
// MODE 0: accumulate row_neg[i] += exp(1 - dist) over valid negatives
// MODE 1: accumulate sum relu(log(rn_i+rn_j)+dist)^2 and count over upper-tri positives
template<int MODE>
__global__ __launch_bounds__(256) void pairs_kernel(
        const unsigned short* __restrict__ Xb, const float* __restrict__ sq,
        const int* __restrict__ tgt, const float* rn_in,
        float* rn_out, float* acc)
{
    const int bi = blockIdx.y, bj = blockIdx.x;
    const int gib = bi * 128, gjb = bj * 64;
    if (MODE == 1 && gjb + 64 <= gib) return;   // whole tile has gj <= gi

    __shared__ __align__(16) unsigned short tA[128 * 128];
    __shared__ __align__(16) unsigned short tB[64 * 128];
    __shared__ float s_sqi[128], s_sqj[64], s_rni[128], s_rnj[64];
    __shared__ int   s_ti[128], s_tj[64];
    __shared__ float s_red[8];

    const int t = threadIdx.x;

    // stage A tile (128 rows x 128 k), XOR-swizzled at 16B granularity
    #pragma unroll
    for (int it = 0; it < 8; ++it) {
        int idx = it * 256 + t;
        int row = idx >> 4, c16 = idx & 15;
        int sw = c16 ^ (row & 7);
        uint4 va = *reinterpret_cast<const uint4*>(Xb + (gib + row) * DIM + c16 * 8);
        *reinterpret_cast<uint4*>(&tA[row * 128 + sw * 8]) = va;
    }
    // stage B tile (64 rows x 128 k)
    #pragma unroll
    for (int it = 0; it < 4; ++it) {
        int idx = it * 256 + t;
        int row = idx >> 4, c16 = idx & 15;
        int sw = c16 ^ (row & 7);
        uint4 vb = *reinterpret_cast<const uint4*>(Xb + (gjb + row) * DIM + c16 * 8);
        *reinterpret_cast<uint4*>(&tB[row * 128 + sw * 8]) = vb;
    }
    if (t < 128) {
        s_sqi[t] = sq[gib + t]; s_ti[t] = tgt[gib + t];
        if (MODE == 1) s_rni[t] = rn_in[gib + t];
    } else if (t < 192) {
        int u = t - 128;
        s_sqj[u] = sq[gjb + u]; s_tj[u] = tgt[gjb + u];
        if (MODE == 1) s_rnj[u] = rn_in[gjb + u];
    }
    __syncthreads();

    const int l = t & 63, w = t >> 6;
    const int lr = l & 15, lg = l >> 4;

    // wave w owns i-rows [w*32, w*32+32), all 64 j
    f32x4 C[2][4] = {};
    #pragma unroll
    for (int ks = 0; ks < 4; ++ks) {
        int c16 = ks * 4 + lg;
        short8 a[2], b[4];
        #pragma unroll
        for (int fi = 0; fi < 2; ++fi) {
            int row = w * 32 + fi * 16 + lr;
            a[fi] = *reinterpret_cast<const short8*>(&tA[row * 128 + (c16 ^ (row & 7)) * 8]);
        }
        #pragma unroll
        for (int fj = 0; fj < 4; ++fj) {
            int row = fj * 16 + lr;
            b[fj] = *reinterpret_cast<const short8*>(&tB[row * 128 + (c16 ^ (row & 7)) * 8]);
        }
        #pragma unroll
        for (int fi = 0; fi < 2; ++fi)
            #pragma unroll
            for (int fj = 0; fj < 4; ++fj)
                C[fi][fj] = __builtin_amdgcn_mfma_f32_16x16x32_bf16(a[fi], b[fj], C[fi][fj], 0, 0, 0);
    }

    // C element (fi,fj,r): i_local = w*32+fi*16+lg*4+r, j_local = fj*16+lr  [m89 layout]
    if (MODE == 0) {
        float racc[2][4] = {};
        #pragma unroll
        for (int fi = 0; fi < 2; ++fi) {
            #pragma unroll
            for (int fj = 0; fj < 4; ++fj) {
                int jl = fj * 16 + lr;
                float sqj = s_sqj[jl];
                int tj = s_tj[jl];
                #pragma unroll
                for (int r = 0; r < 4; ++r) {
                    int il = w * 32 + fi * 16 + lg * 4 + r;
                    float d2 = s_sqi[il] + sqj - 2.0f * C[fi][fj][r];
                    d2 = fmaxf(d2, 0.0f);
                    float dist = (d2 > 0.0f) ? sqrtf(d2) : 0.0f;
                    float e = (s_ti[il] != tj && dist != 0.0f) ? __expf(1.0f - dist) : 0.0f;
                    // sum over the 16 columns held by this 16-lane group
                    e += __shfl_xor(e, 1);
                    e += __shfl_xor(e, 2);
                    e += __shfl_xor(e, 4);
                    e += __shfl_xor(e, 8);
                    racc[fi][r] += e;
                }
            }
        }
        if (lr == 0) {
            #pragma unroll
            for (int fi = 0; fi < 2; ++fi)
                #pragma unroll
                for (int r = 0; r < 4; ++r)
                    atomicAdd(&rn_out[gib + w * 32 + fi * 16 + lg * 4 + r], racc[fi][r]);
        }
    } else {
        float csum = 0.0f, ccnt = 0.0f;
        #pragma unroll
        for (int fi = 0; fi < 2; ++fi) {
            #pragma unroll
            for (int fj = 0; fj < 4; ++fj) {
                int jl = fj * 16 + lr;
                int gj = gjb + jl;
                int tj = s_tj[jl];
                float sqj = s_sqj[jl];
                float rnj = s_rnj[jl];
                #pragma unroll
                for (int r = 0; r < 4; ++r) {
                    int il = w * 32 + fi * 16 + lg * 4 + r;
                    int gi = gib + il;
                    if (s_ti[il] == tj && gi < gj) {
                        float d2 = s_sqi[il] + sqj - 2.0f * C[fi][fj][r];
                        d2 = fmaxf(d2, 0.0f);
                        float dist = (d2 > 0.0f) ? sqrtf(d2) : 0.0f;
                        float J = __logf(s_rni[il] + rnj) + dist;
                        if (J > 0.0f) csum += J * J;
                        ccnt += 1.0f;
                    }
                }
            }
        }
        // reduce across the wave
        #pragma unroll
        for (int m = 32; m; m >>= 1) {
            csum += __shfl_xor(csum, m);
            ccnt += __shfl_xor(ccnt, m);
        }
        if (l == 0) { s_red[w] = csum; s_red[4 + w] = ccnt; }
        __syncthreads();
        if (t == 0) {
            atomicAdd(&acc[0], s_red[0] + s_red[1] + s_red[2] + s_red[3]);
            atomicAdd(&acc[1], s_red[4] + s_red[5] + s_red[6] + s_red[7]);
        }
    }
}

__global__ void finalize_kernel(const float* __restrict__ acc, float* __restrict__ out) {
    out[0] = acc[0] / (2.0f * acc[1]);   // len_p = 2 * upper-tri count
}

extern "C" void kernel_launch(void* const* d_in, const int* in_sizes, int n_in,
                              void* d_out, int out_size, void* d_ws, size_t ws_size,
                              hipStream_t stream)
{
    const float* X  = (const float*)d_in[0];
    const int* tgt  = (const int*)d_in[1];
    float* out      = (float*)d_out;

    char* ws = (char*)d_ws;
    unsigned short* Xb = (unsigned short*)ws;                 // N*D bf16 = 1 MB
    float* sq  = (float*)(ws + (size_t)NROW * DIM * 2);       // N floats
    float* rn  = sq + NROW;                                   // N floats
    float* acc = rn + NROW;                                   // [sum, cnt]

    prep_kernel<<<NROW / 8, 256, 0, stream>>>(X, Xb, sq, rn, acc);
    pairs_kernel<0><<<dim3(64, 32), 256, 0, stream>>>(Xb, sq, tgt, rn, rn, acc);
    pairs_kernel<1><<<dim3(64, 32), 256, 0, stream>>>(Xb, sq, tgt, rn, rn, acc);
    finalize_kernel<<<1, 1, 0, stream>>>(acc, out);
}

// Round 2
// 62.996 us; speedup vs baseline: 1.3657x; 1.3657x over previous
//
#include <hip/hip_runtime.h>
#include <hip/hip_bf16.h>
#include <math.h>

typedef short short8 __attribute__((ext_vector_type(8)));
typedef float f32x4 __attribute__((ext_vector_type(4)));

#define NROW 4096
#define DIM  128
#define NCLS 64
#define CCAP 512
#define MAXM 128

__device__ __forceinline__ unsigned short f2bf(float f) {
    unsigned u = __builtin_bit_cast(unsigned, f);
    unsigned r = (u + 0x7fffu + ((u >> 16) & 1u)) >> 16;   // RNE
    return (unsigned short)r;
}

// ---- prep: fp32 row norms, bf16 copy, zero rn/acc/tick/class counters ----
__global__ __launch_bounds__(256) void prep_kernel(const float* __restrict__ X,
        unsigned short* __restrict__ Xb, float* __restrict__ sq,
        float* __restrict__ rn, float* __restrict__ acc,
        unsigned* __restrict__ tick, int* __restrict__ ccnt)
{
    int t = threadIdx.x;
    int row = blockIdx.x * 8 + (t >> 5);
    int c = t & 31;
    float4 v = *reinterpret_cast<const float4*>(X + (size_t)row * DIM + c * 4);
    float p = v.x * v.x + v.y * v.y + v.z * v.z + v.w * v.w;
    p += __shfl_xor(p, 16, 32);
    p += __shfl_xor(p, 8, 32);
    p += __shfl_xor(p, 4, 32);
    p += __shfl_xor(p, 2, 32);
    p += __shfl_xor(p, 1, 32);
    ushort4 h;
    h.x = f2bf(v.x); h.y = f2bf(v.y); h.z = f2bf(v.z); h.w = f2bf(v.w);
    *reinterpret_cast<ushort4*>(Xb + (size_t)row * DIM + c * 4) = h;
    if (c == 0) { sq[row] = p; rn[row] = 0.0f; }
    if (blockIdx.x == 0) {
        if (t < NCLS) ccnt[t] = 0;
        if (t == 64) { acc[0] = 0.0f; acc[1] = 0.0f; }
        if (t == 65) tick[0] = 0u;
    }
}

// ---- scatter rows into per-class lists ----
__global__ __launch_bounds__(256) void scatter_kernel(const int* __restrict__ tgt,
        int* __restrict__ ccnt, int* __restrict__ list)
{
    int i = blockIdx.x * 256 + threadIdx.x;
    int c = tgt[i];
    int p = atomicAdd(&ccnt[c], 1);
    if (p < CCAP) list[c * CCAP + p] = i;
}

// ---- row_neg: upper-tri 64x64 tiles, fragments direct from global (L2-resident) ----
// each valid pair (gi<gj, diff class, d2>0) contributes exp(1-dist) to rn[gi] AND rn[gj]
__global__ __launch_bounds__(256) void rowneg_kernel(
        const unsigned short* __restrict__ Xb, const float* __restrict__ sq,
        const int* __restrict__ tgt, float* __restrict__ rn)
{
    const int bi = blockIdx.y, bj = blockIdx.x;
    if (bj < bi) return;                       // strictly-lower tiles skipped
    const int gib = bi * 64, gjb = bj * 64;

    __shared__ float s_sqi[64], s_sqj[64], s_cacc[64];
    __shared__ int   s_ti[64], s_tj[64];

    const int t = threadIdx.x;
    if (t < 64)       { s_sqi[t] = sq[gib + t]; s_ti[t] = tgt[gib + t]; }
    else if (t < 128) { int u = t - 64; s_sqj[u] = sq[gjb + u]; s_tj[u] = tgt[gjb + u]; }
    else if (t < 192) { s_cacc[t - 128] = 0.0f; }
    __syncthreads();

    const int w = t >> 6, l = t & 63, lr = l & 15, lg = l >> 4;
    const int arow = gib + w * 16 + lr;

    f32x4 C[4] = {};
    #pragma unroll
    for (int ks = 0; ks < 4; ++ks) {
        int ke = ks * 32 + lg * 8;             // element offset within row
        short8 a = *reinterpret_cast<const short8*>(Xb + (size_t)arow * DIM + ke);
        #pragma unroll
        for (int fj = 0; fj < 4; ++fj) {
            short8 b = *reinterpret_cast<const short8*>(Xb + (size_t)(gjb + fj * 16 + lr) * DIM + ke);
            C[fj] = __builtin_amdgcn_mfma_f32_16x16x32_bf16(a, b, C[fj], 0, 0, 0);
        }
    }

    // C[fj][r]: i = gib + w*16 + lg*4 + r, j = gjb + fj*16 + lr
    const int ibase = w * 16 + lg * 4;
    float sqi[4]; int ti[4];
    #pragma unroll
    for (int r = 0; r < 4; ++r) { sqi[r] = s_sqi[ibase + r]; ti[r] = s_ti[ibase + r]; }

    float racc[4] = {0.f, 0.f, 0.f, 0.f};
    float cacc[4] = {0.f, 0.f, 0.f, 0.f};
    #pragma unroll
    for (int fj = 0; fj < 4; ++fj) {
        int jl = fj * 16 + lr;
        float sqj = s_sqj[jl];
        int   tj  = s_tj[jl];
        int   gj  = gjb + jl;
        #pragma unroll
        for (int r = 0; r < 4; ++r) {
            int gi = gib + ibase + r;
            float d2 = fmaxf(sqi[r] + sqj - 2.0f * C[fj][r], 0.0f);
            float dist = __builtin_amdgcn_sqrtf(d2);
            float e = __expf(1.0f - dist);
            bool valid = (gi < gj) && (ti[r] != tj) && (d2 > 0.0f);
            e = valid ? e : 0.0f;
            racc[r] += e;
            cacc[fj] += e;
        }
    }

    // row sums: reduce across lr (16 lanes)
    #pragma unroll
    for (int r = 0; r < 4; ++r) {
        racc[r] += __shfl_xor(racc[r], 1);
        racc[r] += __shfl_xor(racc[r], 2);
        racc[r] += __shfl_xor(racc[r], 4);
        racc[r] += __shfl_xor(racc[r], 8);
    }
    if (lr == 0) {
        #pragma unroll
        for (int r = 0; r < 4; ++r) atomicAdd(&rn[gib + ibase + r], racc[r]);
    }
    // col sums: reduce across lg (4 groups), combine across waves in LDS
    #pragma unroll
    for (int fj = 0; fj < 4; ++fj) {
        cacc[fj] += __shfl_xor(cacc[fj], 16);
        cacc[fj] += __shfl_xor(cacc[fj], 32);
    }
    if (lg == 0) {
        #pragma unroll
        for (int fj = 0; fj < 4; ++fj) atomicAdd(&s_cacc[fj * 16 + lr], cacc[fj]);
    }
    __syncthreads();
    if (t < 64 && s_cacc[t] != 0.0f) atomicAdd(&rn[gjb + t], s_cacc[t]);
}

// ---- per-class positive-pair loss; last block finalizes ----
__global__ __launch_bounds__(256) void loss_kernel(
        const unsigned short* __restrict__ Xb, const float* __restrict__ X,
        const float* __restrict__ sq, const float* __restrict__ rn,
        const int* __restrict__ ccnt, const int* __restrict__ list,
        float* __restrict__ acc, unsigned* __restrict__ tick, float* __restrict__ out)
{
    const int c = blockIdx.x;
    int m = ccnt[c]; if (m > CCAP) m = CCAP;
    const int mm = m < MAXM ? m : MAXM;

    __shared__ __align__(16) unsigned short tX[MAXM * DIM];
    __shared__ float sqg[MAXM], rng[MAXM];
    __shared__ float s_red[16];

    const int t = threadIdx.x;
    // gathered stage: 4 threads per row, XOR-swizzled 16B chunks
    for (int rr = t >> 2; rr < MAXM; rr += 64) {
        int q4 = t & 3;
        int ri = (rr < mm) ? list[c * CCAP + rr] : -1;
        if (q4 == 0) {
            sqg[rr] = (ri >= 0) ? sq[ri] : 0.0f;
            rng[rr] = (ri >= 0) ? rn[ri] : 0.0f;
        }
        #pragma unroll
        for (int u = 0; u < 4; ++u) {
            int c16 = q4 * 4 + u;
            int sw  = c16 ^ (rr & 7);
            uint4 v = (ri >= 0) ? *reinterpret_cast<const uint4*>(Xb + (size_t)ri * DIM + c16 * 8)
                                : make_uint4(0u, 0u, 0u, 0u);
            *reinterpret_cast<uint4*>(&tX[rr * DIM + sw * 8]) = v;
        }
    }
    __syncthreads();

    const int w = t >> 6, l = t & 63, lr = l & 15, lg = l >> 4;

    f32x4 C[2][8] = {};
    #pragma unroll
    for (int ks = 0; ks < 4; ++ks) {
        int c16b = ks * 4 + lg;
        short8 a[2], b[8];
        #pragma unroll
        for (int fi = 0; fi < 2; ++fi) {
            int row = w * 32 + fi * 16 + lr;
            a[fi] = *reinterpret_cast<const short8*>(&tX[row * DIM + (c16b ^ (row & 7)) * 8]);
        }
        #pragma unroll
        for (int fj = 0; fj < 8; ++fj) {
            int row = fj * 16 + lr;
            b[fj] = *reinterpret_cast<const short8*>(&tX[row * DIM + (c16b ^ (row & 7)) * 8]);
        }
        #pragma unroll
        for (int fi = 0; fi < 2; ++fi)
            #pragma unroll
            for (int fj = 0; fj < 8; ++fj)
                C[fi][fj] = __builtin_amdgcn_mfma_f32_16x16x32_bf16(a[fi], b[fj], C[fi][fj], 0, 0, 0);
    }

    float csum = 0.0f, cpairs = 0.0f;
    #pragma unroll
    for (int fi = 0; fi < 2; ++fi) {
        #pragma unroll
        for (int fj = 0; fj < 8; ++fj) {
            int q = fj * 16 + lr;
            #pragma unroll
            for (int r = 0; r < 4; ++r) {
                int p = w * 32 + fi * 16 + lg * 4 + r;
                if (q < mm && p < q) {
                    float d2 = fmaxf(sqg[p] + sqg[q] - 2.0f * C[fi][fj][r], 0.0f);
                    float dist = __builtin_amdgcn_sqrtf(d2);
                    float J = __logf(rng[p] + rng[q]) + dist;
                    if (J > 0.0f) csum += J * J;
                    cpairs += 1.0f;
                }
            }
        }
    }

    // correctness fallback for improbably large classes (fp32 path, never hot)
    if (m > MAXM) {
        for (int q = MAXM; q < m; ++q) {
            int rq = list[c * CCAP + q];
            float sqq = sq[rq], rnq = rn[rq];
            for (int p = t; p < q; p += 256) {
                int rp = list[c * CCAP + p];
                const float4* xa = reinterpret_cast<const float4*>(X + (size_t)rp * DIM);
                const float4* xb = reinterpret_cast<const float4*>(X + (size_t)rq * DIM);
                float d = 0.0f;
                for (int k = 0; k < 32; ++k) {
                    float4 av = xa[k], bv = xb[k];
                    d += av.x * bv.x + av.y * bv.y + av.z * bv.z + av.w * bv.w;
                }
                float d2 = fmaxf(sq[rp] + sqq - 2.0f * d, 0.0f);
                float dist = __builtin_amdgcn_sqrtf(d2);
                float J = __logf(rn[rp] + rnq) + dist;
                if (J > 0.0f) csum += J * J;
                cpairs += 1.0f;
            }
        }
    }

    #pragma unroll
    for (int mredux = 1; mredux < 64; mredux <<= 1) {
        csum   += __shfl_xor(csum, mredux);
        cpairs += __shfl_xor(cpairs, mredux);
    }
    if (l == 0) { s_red[w] = csum; s_red[8 + w] = cpairs; }
    __syncthreads();
    if (t == 0) {
        float bs = s_red[0] + s_red[1] + s_red[2] + s_red[3];
        float bc = s_red[8] + s_red[9] + s_red[10] + s_red[11];
        atomicAdd(&acc[0], bs);
        atomicAdd(&acc[1], bc);
        __threadfence();
        unsigned old = atomicAdd(tick, 1u);
        if (old == NCLS - 1) {
            float s  = atomicAdd(&acc[0], 0.0f);   // coherent device-scope read
            float n2 = atomicAdd(&acc[1], 0.0f);
            out[0] = s / (2.0f * n2);              // len_p = 2 * upper-tri count
        }
    }
}

extern "C" void kernel_launch(void* const* d_in, const int* in_sizes, int n_in,
                              void* d_out, int out_size, void* d_ws, size_t ws_size,
                              hipStream_t stream)
{
    const float* X  = (const float*)d_in[0];
    const int* tgt  = (const int*)d_in[1];
    float* out      = (float*)d_out;

    char* ws = (char*)d_ws;
    unsigned short* Xb = (unsigned short*)ws;                       // 1 MB
    float* sq   = (float*)(ws + (size_t)NROW * DIM * 2);            // 16 KB
    float* rn   = sq + NROW;                                        // 16 KB
    float* acc  = rn + NROW;                                        // 2 floats
    unsigned* tick = (unsigned*)(acc + 4);
    int* ccnt   = (int*)(tick + 4);                                 // 64 ints
    int* list   = ccnt + NCLS;                                      // 128 KB

    prep_kernel<<<NROW / 8, 256, 0, stream>>>(X, Xb, sq, rn, acc, tick, ccnt);
    scatter_kernel<<<NROW / 256, 256, 0, stream>>>(tgt, ccnt, list);
    rowneg_kernel<<<dim3(64, 64), 256, 0, stream>>>(Xb, sq, tgt, rn);
    loss_kernel<<<NCLS, 256, 0, stream>>>(Xb, X, sq, rn, ccnt, list, acc, tick, out);
}

// Round 3
// 40.370 us; speedup vs baseline: 2.1312x; 1.5605x over previous
//
#include <hip/hip_runtime.h>
#include <hip/hip_bf16.h>
#include <math.h>

typedef short short8 __attribute__((ext_vector_type(8)));
typedef float f32x4 __attribute__((ext_vector_type(4)));

#define NROW 4096
#define DIM  128
#define NCLS 64
#define CCAP 512
#define MAXM 128

typedef __attribute__((address_space(3))) unsigned lds_u32;
typedef const __attribute__((address_space(1))) unsigned glb_u32;

__device__ __forceinline__ void gload16(const void* g, void* lds) {
    // 16B per lane, LDS dest = wave-uniform base + lane*16, global src per-lane
    __builtin_amdgcn_global_load_lds((glb_u32*)g, (lds_u32*)lds, 16, 0, 0);
}

__device__ __forceinline__ unsigned short f2bf(float f) {
    unsigned u = __builtin_bit_cast(unsigned, f);
    unsigned r = (u + 0x7fffu + ((u >> 16) & 1u)) >> 16;   // RNE
    return (unsigned short)r;
}

// ---- prep: fp32 row norms, bf16 copy, zero rn/acc/tick/class counters ----
__global__ __launch_bounds__(256) void prep_kernel(const float* __restrict__ X,
        unsigned short* __restrict__ Xb, float* __restrict__ sq,
        float* __restrict__ rn, float* __restrict__ acc,
        unsigned* __restrict__ tick, int* __restrict__ ccnt)
{
    int t = threadIdx.x;
    int row = blockIdx.x * 8 + (t >> 5);
    int c = t & 31;
    float4 v = *reinterpret_cast<const float4*>(X + (size_t)row * DIM + c * 4);
    float p = v.x * v.x + v.y * v.y + v.z * v.z + v.w * v.w;
    p += __shfl_xor(p, 16, 32);
    p += __shfl_xor(p, 8, 32);
    p += __shfl_xor(p, 4, 32);
    p += __shfl_xor(p, 2, 32);
    p += __shfl_xor(p, 1, 32);
    ushort4 h;
    h.x = f2bf(v.x); h.y = f2bf(v.y); h.z = f2bf(v.z); h.w = f2bf(v.w);
    *reinterpret_cast<ushort4*>(Xb + (size_t)row * DIM + c * 4) = h;
    if (c == 0) { sq[row] = p; rn[row] = 0.0f; }
    if (blockIdx.x == 0) {
        if (t < NCLS) ccnt[t] = 0;
        if (t == 64) { acc[0] = 0.0f; acc[1] = 0.0f; }
        if (t == 65) tick[0] = 0u;
    }
}

// ---- row_neg: upper-tri 64x64 tiles, LDS-staged via global_load_lds (pre-swizzled src) ----
// diagonal blocks additionally scatter their rows into per-class lists
__global__ __launch_bounds__(256) void rowneg_kernel(
        const unsigned short* __restrict__ Xb, const float* __restrict__ sq,
        const int* __restrict__ tgt, float* __restrict__ rn,
        int* __restrict__ ccnt, int* __restrict__ list)
{
    const int bi = blockIdx.y, bj = blockIdx.x;
    if (bj < bi) return;
    const int gib = bi * 64, gjb = bj * 64;

    __shared__ __align__(16) unsigned short tA[64 * 128];
    __shared__ __align__(16) unsigned short tB[64 * 128];
    __shared__ float s_sqi[64], s_sqj[64];
    __shared__ float s_cacc[4][64];
    __shared__ int   s_ti[64], s_tj[64];

    const int t = threadIdx.x;
    const int w = t >> 6, l = t & 63, lr = l & 15, lg = l >> 4;

    // stage A,B: 16 issues each of 1KB; linear LDS dest, swizzled global source
    #pragma unroll
    for (int k = 0; k < 4; ++k) {
        int q = w * 4 + k;                     // 1KB chunk
        int row = q * 4 + (l >> 4);            // 4 rows per KB
        int c16 = l & 15;
        int sc = c16 ^ (row & 7);              // inverse-swizzled source chunk
        gload16(Xb + (size_t)(gib + row) * DIM + sc * 8, &tA[q * 512]);
        gload16(Xb + (size_t)(gjb + row) * DIM + sc * 8, &tB[q * 512]);
    }
    if (t < 64)       { s_sqi[t] = sq[gib + t]; s_ti[t] = tgt[gib + t]; }
    else if (t < 128) { int u = t - 64; s_sqj[u] = sq[gjb + u]; s_tj[u] = tgt[gjb + u]; }
    if (bi == bj && t >= 128 && t < 192) {     // embedded scatter (once per row)
        int row = gib + (t - 128);
        int cls = tgt[row];
        int p = atomicAdd(&ccnt[cls], 1);
        if (p < CCAP) list[cls * CCAP + p] = row;
    }
    __syncthreads();

    const int arow = w * 16 + lr;
    f32x4 C[4] = {};
    #pragma unroll
    for (int ks = 0; ks < 4; ++ks) {
        int c = ks * 4 + lg;
        short8 a = *reinterpret_cast<const short8*>(&tA[arow * 128 + ((c ^ (arow & 7)) * 8)]);
        #pragma unroll
        for (int fj = 0; fj < 4; ++fj) {
            int brow = fj * 16 + lr;
            short8 b = *reinterpret_cast<const short8*>(&tB[brow * 128 + ((c ^ (brow & 7)) * 8)]);
            C[fj] = __builtin_amdgcn_mfma_f32_16x16x32_bf16(a, b, C[fj], 0, 0, 0);
        }
    }

    // C[fj][r]: i = gib + w*16 + lg*4 + r, j = gjb + fj*16 + lr
    const int ibase = w * 16 + lg * 4;
    float sqi[4]; int ti[4];
    #pragma unroll
    for (int r = 0; r < 4; ++r) { sqi[r] = s_sqi[ibase + r]; ti[r] = s_ti[ibase + r]; }

    float racc[4] = {0.f, 0.f, 0.f, 0.f};
    float cacc[4] = {0.f, 0.f, 0.f, 0.f};
    #pragma unroll
    for (int fj = 0; fj < 4; ++fj) {
        int jl = fj * 16 + lr;
        float sqj = s_sqj[jl];
        int   tj  = s_tj[jl];
        int   gj  = gjb + jl;
        #pragma unroll
        for (int r = 0; r < 4; ++r) {
            int gi = gib + ibase + r;
            float d2 = fmaxf(sqi[r] + sqj - 2.0f * C[fj][r], 0.0f);
            float dist = __builtin_amdgcn_sqrtf(d2);
            float e = __expf(1.0f - dist);
            bool valid = (gi < gj) && (ti[r] != tj) && (d2 > 0.0f);
            e = valid ? e : 0.0f;
            racc[r] += e;
            cacc[fj] += e;
        }
    }

    // row sums: reduce across lr (16 lanes) -> global atomics
    #pragma unroll
    for (int r = 0; r < 4; ++r) {
        racc[r] += __shfl_xor(racc[r], 1);
        racc[r] += __shfl_xor(racc[r], 2);
        racc[r] += __shfl_xor(racc[r], 4);
        racc[r] += __shfl_xor(racc[r], 8);
    }
    if (lr == 0) {
        #pragma unroll
        for (int r = 0; r < 4; ++r) atomicAdd(&rn[gib + ibase + r], racc[r]);
    }
    // col sums: reduce across lg within wave, per-wave LDS slice, sum 4 at the end
    #pragma unroll
    for (int fj = 0; fj < 4; ++fj) {
        cacc[fj] += __shfl_xor(cacc[fj], 16);
        cacc[fj] += __shfl_xor(cacc[fj], 32);
    }
    if (lg == 0) {
        #pragma unroll
        for (int fj = 0; fj < 4; ++fj) s_cacc[w][fj * 16 + lr] = cacc[fj];
    }
    __syncthreads();
    if (t < 64) {
        float cs = s_cacc[0][t] + s_cacc[1][t] + s_cacc[2][t] + s_cacc[3][t];
        if (cs != 0.0f) atomicAdd(&rn[gjb + t], cs);
    }
}

// ---- per-class positive-pair loss; last block finalizes ----
__global__ __launch_bounds__(256) void loss_kernel(
        const unsigned short* __restrict__ Xb, const float* __restrict__ X,
        const float* __restrict__ sq, const float* __restrict__ rn,
        const int* __restrict__ ccnt, const int* __restrict__ list,
        float* __restrict__ acc, unsigned* __restrict__ tick, float* __restrict__ out)
{
    const int c = blockIdx.x;
    int m = ccnt[c]; if (m > CCAP) m = CCAP;
    const int mm = m < MAXM ? m : MAXM;
    const int nfj = (mm + 15) >> 4;            // active 16-col blocks

    __shared__ __align__(16) unsigned short tX[MAXM * DIM];
    __shared__ float sqg[MAXM], rng[MAXM];
    __shared__ int   s_idx[MAXM];
    __shared__ float s_red[16];

    const int t = threadIdx.x;
    const int w = t >> 6, l = t & 63, lr = l & 15, lg = l >> 4;

    if (t < MAXM) s_idx[t] = (t < mm) ? list[c * CCAP + t] : 0;   // pad -> row 0 (guarded later)
    __syncthreads();

    if (t < MAXM) {
        int ri = s_idx[t];
        sqg[t] = (t < mm) ? sq[ri] : 0.0f;
        rng[t] = (t < mm) ? rn[ri] : 0.0f;
    }
    // gathered stage: 32 issues of 1KB, per-lane gather + swizzle source, linear LDS
    #pragma unroll
    for (int k = 0; k < 8; ++k) {
        int q = w * 8 + k;
        int row = q * 4 + (l >> 4);
        if (row < ((mm + 3) & ~3)) {           // skip fully-pad KBs beyond mm
            int c16 = l & 15;
            int sc = c16 ^ (row & 7);
            gload16(Xb + (size_t)s_idx[row] * DIM + sc * 8, &tX[q * 512]);
        }
    }
    __syncthreads();

    f32x4 C[2][8] = {};
    #pragma unroll
    for (int ks = 0; ks < 4; ++ks) {
        int cb = ks * 4 + lg;
        short8 a[2], b[8];
        #pragma unroll
        for (int fi = 0; fi < 2; ++fi) {
            int row = w * 32 + fi * 16 + lr;
            a[fi] = *reinterpret_cast<const short8*>(&tX[row * DIM + ((cb ^ (row & 7)) * 8)]);
        }
        #pragma unroll
        for (int fj = 0; fj < 8; ++fj) {
            int row = fj * 16 + lr;
            b[fj] = *reinterpret_cast<const short8*>(&tX[row * DIM + ((cb ^ (row & 7)) * 8)]);
        }
        #pragma unroll
        for (int fi = 0; fi < 2; ++fi) {
            if (w * 32 + fi * 16 < mm) {
                #pragma unroll
                for (int fj = 0; fj < 8; ++fj)
                    if (fj < nfj)
                        C[fi][fj] = __builtin_amdgcn_mfma_f32_16x16x32_bf16(a[fi], b[fj], C[fi][fj], 0, 0, 0);
            }
        }
    }

    float csum = 0.0f, cpairs = 0.0f;
    #pragma unroll
    for (int fi = 0; fi < 2; ++fi) {
        if (w * 32 + fi * 16 < mm) {
            #pragma unroll
            for (int fj = 0; fj < 8; ++fj) {
                if (fj < nfj) {
                    int q = fj * 16 + lr;
                    #pragma unroll
                    for (int r = 0; r < 4; ++r) {
                        int p = w * 32 + fi * 16 + lg * 4 + r;
                        if (q < mm && p < q) {
                            float d2 = fmaxf(sqg[p] + sqg[q] - 2.0f * C[fi][fj][r], 0.0f);
                            float dist = __builtin_amdgcn_sqrtf(d2);
                            float J = __logf(rng[p] + rng[q]) + dist;
                            if (J > 0.0f) csum += J * J;
                            cpairs += 1.0f;
                        }
                    }
                }
            }
        }
    }

    // correctness fallback for improbably large classes (fp32 path, never hot)
    if (m > MAXM) {
        for (int q = MAXM; q < m; ++q) {
            int rq = list[c * CCAP + q];
            float sqq = sq[rq], rnq = rn[rq];
            for (int p = t; p < q; p += 256) {
                int rp = list[c * CCAP + p];
                const float4* xa = reinterpret_cast<const float4*>(X + (size_t)rp * DIM);
                const float4* xb = reinterpret_cast<const float4*>(X + (size_t)rq * DIM);
                float d = 0.0f;
                for (int k = 0; k < 32; ++k) {
                    float4 av = xa[k], bv = xb[k];
                    d += av.x * bv.x + av.y * bv.y + av.z * bv.z + av.w * bv.w;
                }
                float d2 = fmaxf(sq[rp] + sqq - 2.0f * d, 0.0f);
                float dist = __builtin_amdgcn_sqrtf(d2);
                float J = __logf(rn[rp] + rnq) + dist;
                if (J > 0.0f) csum += J * J;
                cpairs += 1.0f;
            }
        }
    }

    #pragma unroll
    for (int mr = 1; mr < 64; mr <<= 1) {
        csum   += __shfl_xor(csum, mr);
        cpairs += __shfl_xor(cpairs, mr);
    }
    if (l == 0) { s_red[w] = csum; s_red[8 + w] = cpairs; }
    __syncthreads();
    if (t == 0) {
        float bs = s_red[0] + s_red[1] + s_red[2] + s_red[3];
        float bc = s_red[8] + s_red[9] + s_red[10] + s_red[11];
        atomicAdd(&acc[0], bs);
        atomicAdd(&acc[1], bc);
        __threadfence();
        unsigned old = atomicAdd(tick, 1u);
        if (old == NCLS - 1) {
            float s  = atomicAdd(&acc[0], 0.0f);   // coherent device-scope read
            float n2 = atomicAdd(&acc[1], 0.0f);
            out[0] = s / (2.0f * n2);              // len_p = 2 * upper-tri count
        }
    }
}

extern "C" void kernel_launch(void* const* d_in, const int* in_sizes, int n_in,
                              void* d_out, int out_size, void* d_ws, size_t ws_size,
                              hipStream_t stream)
{
    const float* X  = (const float*)d_in[0];
    const int* tgt  = (const int*)d_in[1];
    float* out      = (float*)d_out;

    char* ws = (char*)d_ws;
    unsigned short* Xb = (unsigned short*)ws;                       // 1 MB
    float* sq   = (float*)(ws + (size_t)NROW * DIM * 2);            // 16 KB
    float* rn   = sq + NROW;                                        // 16 KB
    float* acc  = rn + NROW;                                        // 2 floats
    unsigned* tick = (unsigned*)(acc + 4);
    int* ccnt   = (int*)(tick + 4);                                 // 64 ints
    int* list   = ccnt + NCLS;                                      // 128 KB

    prep_kernel<<<NROW / 8, 256, 0, stream>>>(X, Xb, sq, rn, acc, tick, ccnt);
    rowneg_kernel<<<dim3(64, 64), 256, 0, stream>>>(Xb, sq, tgt, rn, ccnt, list);
    loss_kernel<<<NCLS, 256, 0, stream>>>(Xb, X, sq, rn, ccnt, list, acc, tick, out);
}